// Round 7
// baseline (163.177 us; speedup 1.0000x reference)
//
#include <hip/hip_runtime.h>

#define D_DIM 512

__device__ __forceinline__ float flog2(float x) {
    return __builtin_amdgcn_logf(x);   // bare v_log_f32; inputs >= ~4e-6, no denormal wrapper
}

// ---- per-row sums: E[row] = sum_d x*log2(x). One wave per row, 4 rows/block.
__global__ __launch_bounds__(256)
void jsd_entropy_kernel(const float* __restrict__ a,
                        const float* __restrict__ b,
                        float* __restrict__ E, int N, int M) {
    int wave = threadIdx.x >> 6;
    int lane = threadIdx.x & 63;
    int row = blockIdx.x * 4 + wave;
    if (row >= N + M) return;
    const float* src = (row < N) ? (a + (size_t)row * D_DIM)
                                 : (b + (size_t)(row - N) * D_DIM);
    float s = 0.f;
#pragma unroll
    for (int d = lane; d < D_DIM; d += 64) {
        float x = src[d];
        s = fmaf(x, flog2(x), s);
    }
#pragma unroll
    for (int off = 32; off > 0; off >>= 1) s += __shfl_down(s, off, 64);
    if (lane == 0) E[row] = s;
}

// ---- main: out[i,j] = 1 - 0.5*S_ij + 0.5*(Ea[i] + Eb[j]),  S_ij = sum_d t*log2 t
// NO LDS, NO BARRIERS: every wave free-runs. 4x4 fragments loaded straight from
// global (a-loads broadcast across 16 same-ty lanes; b-loads hit 16 L2-resident
// lines). Double-buffered fragment prefetch hides ~200cy L2 latency under
// ~768cy of compute. R3-R6 showed the issue stream is at its 98.3k cy/SIMD
// floor and all residual time was barrier-lockstep idle -- this removes it.
constexpr int BN = 64, BM = 64;
constexpr int DSPLIT = 128;          // d per block; z = 4 -> 1024 blocks
constexpr int NG = DSPLIT / 4;       // float4 groups per block

__global__ __launch_bounds__(256, 4)
void jsd_main_kernel(const float* __restrict__ a, const float* __restrict__ b,
                     const float* __restrict__ Ea, const float* __restrict__ Eb,
                     float* __restrict__ out, int N, int M) {
    const int tid = threadIdx.x;          // 256 = 16x16
    const int tx = tid & 15, ty = tid >> 4;
    const int row0 = blockIdx.y * BN + ty * 4;   // this thread's 4 a-rows
    const int col0 = blockIdx.x * BM + tx * 4;   // this thread's 4 b-rows
    const int dStart = blockIdx.z * DSPLIT;

    const float* ap = a + (size_t)row0 * D_DIM + dStart;
    const float* bp = b + (size_t)col0 * D_DIM + dStart;

    float acc[4][4] = {};
    float4 A0[4], B0[4], A1[4], B1[4];

#define LOADG(BA, BB, g)                                                     \
    do {                                                                     \
        _Pragma("unroll")                                                    \
        for (int r = 0; r < 4; ++r) {                                        \
            BA[r] = *(const float4*)(ap + (size_t)r * D_DIM + (g) * 4);      \
            BB[r] = *(const float4*)(bp + (size_t)r * D_DIM + (g) * 4);      \
        }                                                                    \
    } while (0)

#define COMPG(BA, BB)                                                        \
    do {                                                                     \
        _Pragma("unroll")                                                    \
        for (int d = 0; d < 4; ++d) {                                        \
            float ar[4], br[4];                                              \
            _Pragma("unroll")                                                \
            for (int r = 0; r < 4; ++r) {                                    \
                ar[r] = ((const float*)&BA[r])[d];                           \
                br[r] = ((const float*)&BB[r])[d];                           \
            }                                                                \
            _Pragma("unroll")                                                \
            for (int r = 0; r < 4; ++r)                                      \
                _Pragma("unroll")                                            \
                for (int c = 0; c < 4; ++c) {                                \
                    float t = ar[r] + br[c];                                 \
                    acc[r][c] = fmaf(t, flog2(t), acc[r][c]);                \
                }                                                            \
        }                                                                    \
    } while (0)

    LOADG(A0, B0, 0);
    for (int g = 0; g < NG; g += 2) {
        if (g + 1 < NG) LOADG(A1, B1, g + 1);
        COMPG(A0, B0);
        if (g + 2 < NG) LOADG(A0, B0, g + 2);
        if (g + 1 < NG) COMPG(A1, B1);
    }
#undef LOADG
#undef COMPG

    // epilogue: z==0 folds affine term; all z-slices atomicAdd (out pre-zeroed)
    const bool lead = (blockIdx.z == 0);
#pragma unroll
    for (int r = 0; r < 4; ++r) {
        int i = row0 + r;
        float ea = lead ? Ea[i] : 0.f;
        float* p = out + (size_t)i * M + col0;
#pragma unroll
        for (int c = 0; c < 4; ++c) {
            float v = -0.5f * acc[r][c];
            if (lead) v += 1.0f + 0.5f * (ea + Eb[col0 + c]);
            atomicAdd(p + c, v);
        }
    }
}

extern "C" void kernel_launch(void* const* d_in, const int* in_sizes, int n_in,
                              void* d_out, int out_size, void* d_ws, size_t ws_size,
                              hipStream_t stream) {
    const float* a = (const float*)d_in[0];
    const float* b = (const float*)d_in[1];
    const int N = in_sizes[0] / D_DIM;   // 1024
    const int M = in_sizes[1] / D_DIM;   // 1024
    float* E = (float*)d_ws;             // Ea[0..N), Eb[N..N+M)

    hipMemsetAsync(d_out, 0, (size_t)out_size * sizeof(float), stream);
    jsd_entropy_kernel<<<(N + M + 3) / 4, 256, 0, stream>>>(a, b, E, N, M);

    dim3 grid(M / BM, N / BN, D_DIM / DSPLIT);   // 16 x 16 x 4 = 1024 blocks
    jsd_main_kernel<<<grid, 256, 0, stream>>>(a, b, E, E + N, (float*)d_out, N, M);
}